// Round 6
// baseline (240.818 us; speedup 1.0000x reference)
//
#include <hip/hip_runtime.h>
#include <hip/hip_bf16.h>

// TorchNeighborList on MI355X. Output: FLOAT32, pairs[K,2] | diff[K,3] | dist[K].
// R5: 146us across 11 nodes; every kernel tiny, time dominated by serialized
// small dispatches + constant harness d_ws poison fill (~43us). R6: ONE
// persistent kernel (256 blocks x 1024 thr = 1 block/CU, guaranteed resident;
// __launch_bounds__(1024) caps VGPR<=128) with a device-scope atomic grid
// barrier between phases. 2 nodes total (memset + kernel).
// Ordering contract (unchanged, passing since R3): atom i ascending ->
// 27-stencil cart3(1,1,1) row-major -> within cell ascending t = i*27+p.
// All f32 math via _rn intrinsics (no FMA contraction) to bit-match numpy/jax.

#define CUTOFF 5.0f
#define WEPS   1e-7f
#define PIMG   27
#define G      36
#define NCELLS (G*G*G)          // 46656
#define NBLK   256
#define NTHR   1024
#define TOTT   (NBLK*NTHR)      // 262144
#define CCH    1024             // cells per scan chunk
#define NCHC   46               // ceil((NCELLS+1)/CCH)
#define PCH    6144             // pair-slots per block in phase-7 scan (6 tiles x 1024)

// device-scope grid barrier: monotonic counter, release/acquire fences.
// Safe because grid == 1 block/CU (all blocks co-resident).
__device__ __forceinline__ void gsync(int* bar, int phase) {
  __syncthreads();
  if (threadIdx.x == 0) {
    __threadfence();                       // release: L2 writeback (agent scope)
    atomicAdd(bar, 1);
    int target = NBLK * phase;
    while (atomicAdd(bar, 0) < target) __builtin_amdgcn_s_sleep(2);
    __threadfence();                       // acquire: invalidate stale lines
  }
  __syncthreads();
}

// block-wide exclusive scan over 1024 threads (16 waves); returns excl prefix,
// writes block total. lds must hold >=16 ints. Contains 3 __syncthreads.
__device__ __forceinline__ int block_exscan(int v, int* lds, int* total) {
  int tid = threadIdx.x, lane = tid & 63, wave = tid >> 6;
  int x = v;
#pragma unroll
  for (int off = 1; off < 64; off <<= 1) {
    int y = __shfl_up(x, off);
    if (lane >= off) x += y;
  }
  if (lane == 63) lds[wave] = x;
  __syncthreads();
  if (wave == 0) {
    int wv = (lane < 16) ? lds[lane] : 0;
#pragma unroll
    for (int off = 1; off < 16; off <<= 1) {
      int y = __shfl_up(wv, off);
      if (lane >= off) wv += y;
    }
    if (lane < 16) lds[lane] = wv;        // inclusive over wave sums
  }
  __syncthreads();
  int wbase = (wave == 0) ? 0 : lds[wave - 1];
  *total = lds[15];
  __syncthreads();                         // protect lds for next call
  return wbase + x - v;
}

__device__ __forceinline__ void inv_diag3(const float* __restrict__ cell, float inv[9]) {
  float c[9];
#pragma unroll
  for (int i = 0; i < 9; i++) c[i] = cell[i];
  float a00=c[0],a01=c[1],a02=c[2],a10=c[3],a11=c[4],a12=c[5],a20=c[6],a21=c[7],a22=c[8];
  float m00 = __fsub_rn(__fmul_rn(a11,a22), __fmul_rn(a12,a21));
  float m01 = __fsub_rn(__fmul_rn(a10,a22), __fmul_rn(a12,a20));
  float m02 = __fsub_rn(__fmul_rn(a10,a21), __fmul_rn(a11,a20));
  float det = __fadd_rn(__fsub_rn(__fmul_rn(a00,m00), __fmul_rn(a01,m01)), __fmul_rn(a02,m02));
  inv[0] = __fdiv_rn(m00, det);
  inv[1] = __fdiv_rn(__fsub_rn(__fmul_rn(a02,a21), __fmul_rn(a01,a22)), det);
  inv[2] = __fdiv_rn(__fsub_rn(__fmul_rn(a01,a12), __fmul_rn(a02,a11)), det);
  inv[3] = __fdiv_rn(__fsub_rn(__fmul_rn(a12,a20), __fmul_rn(a10,a22)), det);
  inv[4] = __fdiv_rn(__fsub_rn(__fmul_rn(a00,a22), __fmul_rn(a02,a20)), det);
  inv[5] = __fdiv_rn(__fsub_rn(__fmul_rn(a02,a10), __fmul_rn(a00,a12)), det);
  inv[6] = __fdiv_rn(m02, det);
  inv[7] = __fdiv_rn(__fsub_rn(__fmul_rn(a01,a20), __fmul_rn(a00,a21)), det);
  inv[8] = __fdiv_rn(__fsub_rn(__fmul_rn(a00,a11), __fmul_rn(a01,a10)), det);
}

// per-axis image options; p-component order ascending so combos enumerate in
// ascending stencil index p (reference stable-sort key order).
__device__ __forceinline__ int axis_opts(float w, float cdiag, int* pcomp, int* cellv,
                                         float* shv) {
  int cc = (int)floorf(__fdiv_rn(w, CUTOFF));
  int k = 0;
  if (cc >= 29) {
    float wp = __fsub_rn(w, cdiag);
    int c2 = (int)floorf(__fdiv_rn(wp, CUTOFF)) + 2;
    if ((unsigned)c2 < G) { pcomp[k] = 0; cellv[k] = c2; shv[k] = __fsub_rn(0.0f, cdiag); k++; }
  }
  pcomp[k] = 1; cellv[k] = cc + 2; shv[k] = 0.0f; k++;
  if (cc <= 2) {
    float wp = __fadd_rn(w, cdiag);
    int c2 = (int)floorf(__fdiv_rn(wp, CUTOFF)) + 2;
    if ((unsigned)c2 < G) { pcomp[k] = 2; cellv[k] = c2; shv[k] = cdiag; k++; }
  }
  return k;
}

__global__ void __launch_bounds__(NTHR)
k_fused(const float* __restrict__ pos, const float* __restrict__ cell,
        float* __restrict__ out, int n, int K,
        int* bar, int* Mtot, int* counts, int* fill, int* starts,
        float4* wrapped, int* chunkSums, int* csA, int* blockSum, int* csB,
        int* poff, float4* cdata, int cap) {
  __shared__ int lds[32];
  const int tid = threadIdx.x, blk = blockIdx.x;
  const int gtid = blk * NTHR + tid;
  const int n27 = n * PIMG;

  // ---- P1: wrap + per-atom image binning ----
  for (int i = gtid; i < n; i += TOTT) {
    float inv[9];
    inv_diag3(cell, inv);
    float px = pos[3*i], py = pos[3*i+1], pz = pos[3*i+2];
    float m[3];
#pragma unroll
    for (int col = 0; col < 3; col++) {
      float s = __fadd_rn(__fadd_rn(__fmul_rn(px, inv[col]), __fmul_rn(py, inv[3+col])),
                          __fmul_rn(pz, inv[6+col]));
      s = __fadd_rn(s, WEPS);
      float t = __fsub_rn(s, floorf(s));
      m[col] = __fsub_rn(t, WEPS);
    }
    float w[3];
#pragma unroll
    for (int col = 0; col < 3; col++)
      w[col] = __fadd_rn(__fadd_rn(__fmul_rn(m[0], cell[col]), __fmul_rn(m[1], cell[3+col])),
                         __fmul_rn(m[2], cell[6+col]));
    wrapped[i] = make_float4(w[0], w[1], w[2], 0.0f);
    int px_[2], py_[2], pz_[2], cx_[2], cy_[2], cz_[2];
    float sx_[2], sy_[2], sz_[2];
    int nx = axis_opts(w[0], cell[0], px_, cx_, sx_);
    int ny = axis_opts(w[1], cell[4], py_, cy_, sy_);
    int nz = axis_opts(w[2], cell[8], pz_, cz_, sz_);
    for (int a = 0; a < nx; a++)
      for (int b = 0; b < ny; b++)
        for (int c = 0; c < nz; c++)
          atomicAdd(&counts[(cx_[a] * G + cy_[b]) * G + cz_[c]], 1);
  }
  gsync(bar, 1);

  // ---- P2: per-chunk exclusive scan of cell counts (chunk = 1024 cells) ----
  {
    int c = blk * CCH + tid;
    int inr = (blk < NCHC) && (c <= NCELLS);
    int v = inr ? counts[c] : 0;
    int total;
    int excl = block_exscan(v, lds, &total);
    if (inr) starts[c] = excl;
    if (blk < NCHC && tid == 0) chunkSums[blk] = total;
  }
  gsync(bar, 2);

  // ---- P3: scan chunk sums (block 0) ----
  if (blk == 0) {
    int v = (tid < NCHC) ? chunkSums[tid] : 0;
    int total;
    int excl = block_exscan(v, lds, &total);
    if (tid < NCHC) csA[tid] = excl;
  }
  gsync(bar, 3);

  // ---- P4: scatter images into cdata ----
  for (int i = gtid; i < n; i += TOTT) {
    float4 w = wrapped[i];
    int px_[2], py_[2], pz_[2], cx_[2], cy_[2], cz_[2];
    float sx_[2], sy_[2], sz_[2];
    int nx = axis_opts(w.x, cell[0], px_, cx_, sx_);
    int ny = axis_opts(w.y, cell[4], py_, cy_, sy_);
    int nz = axis_opts(w.z, cell[8], pz_, cz_, sz_);
    for (int a = 0; a < nx; a++)
      for (int b = 0; b < ny; b++)
        for (int c = 0; c < nz; c++) {
          int cid = (cx_[a] * G + cy_[b]) * G + cz_[c];
          int p = (px_[a] * 3 + py_[b]) * 3 + pz_[c];
          int slot = starts[cid] + csA[cid >> 10] + atomicAdd(&fill[cid], 1);
          if ((unsigned)slot >= (unsigned)cap) continue;
          cdata[slot] = make_float4(__fadd_rn(w.x, sx_[a]), __fadd_rn(w.y, sy_[b]),
                                    __fadd_rn(w.z, sz_[c]), __int_as_float(i * PIMG + p));
        }
  }
  gsync(bar, 4);

  // ---- P5: per-cell insertion sort by padded index t ----
  for (int c = gtid; c < NCELLS; c += TOTT) {
    int s = starts[c] + csA[c >> 10];
    int e = starts[c + 1] + csA[(c + 1) >> 10];
    for (int a = s + 1; a < e; a++) {
      float4 key = cdata[a];
      int kk = __float_as_int(key.w);
      int b = a - 1;
      while (b >= s && __float_as_int(cdata[b].w) > kk) { cdata[b + 1] = cdata[b]; b--; }
      cdata[b + 1] = key;
    }
  }
  gsync(bar, 5);

  // ---- P7: fused per-(atom,stencil) pair count + per-block chunk scan ----
  {
    int carry = 0;
#pragma unroll
    for (int j = 0; j < PCH / NTHR; j++) {
      int idx = blk * PCH + j * NTHR + tid;
      int cnt = 0;
      if (idx < n27) {
        int i = idx / PIMG, s27 = idx - i * PIMG;
        int dx = s27 / 9 - 1, dy = (s27 / 3) % 3 - 1, dz = s27 % 3 - 1;
        float4 w = wrapped[i];
        int cx = (int)floorf(__fdiv_rn(w.x, CUTOFF)) + 2 + dx;
        int cy = (int)floorf(__fdiv_rn(w.y, CUTOFF)) + 2 + dy;
        int cz = (int)floorf(__fdiv_rn(w.z, CUTOFF)) + 2 + dz;
        int cid = (cx * G + cy) * G + cz;
        int s = starts[cid] + csA[cid >> 10];
        int e = starts[cid + 1] + csA[(cid + 1) >> 10];
        for (int q = s; q < e; q++) {
          float4 f = cdata[q];
          float ax = __fsub_rn(f.x, w.x), ay = __fsub_rn(f.y, w.y), az = __fsub_rn(f.z, w.z);
          float d = __fsqrt_rn(__fadd_rn(__fadd_rn(__fmul_rn(ax, ax), __fmul_rn(ay, ay)),
                                         __fmul_rn(az, az)));
          if (d < CUTOFF && d > 0.01f) cnt++;
        }
      }
      int total;
      int excl = block_exscan(cnt, lds, &total);
      if (idx < n27) poff[idx] = carry + excl;
      carry += total;
    }
    blockSum[blk] = carry;
  }
  gsync(bar, 6);

  // ---- P8: scan block sums (block 0) ----
  if (blk == 0) {
    int v = (tid < NBLK) ? blockSum[tid] : 0;
    int total;
    int excl = block_exscan(v, lds, &total);
    if (tid < NBLK) csB[tid] = excl;
    if (tid == NBLK - 1) *Mtot = excl + v;
  }
  gsync(bar, 7);

  // ---- P9: emit ----
  if (gtid == 0 && *Mtot != K) {
    int M = *Mtot;
    float code = (M < K) ? (1000000.0f + (float)min(K - M, 100000))
                         : (2000000.0f + (float)min(M - K, 100000));
    for (int t = 0; t < 256; t++) out[t] = code;
  }
  for (int t = gtid; t < n27; t += TOTT) {
    int i = t / PIMG, s27 = t - i * PIMG;
    int dx = s27 / 9 - 1, dy = (s27 / 3) % 3 - 1, dz = s27 % 3 - 1;
    float4 w = wrapped[i];
    int cx = (int)floorf(__fdiv_rn(w.x, CUTOFF)) + 2 + dx;
    int cy = (int)floorf(__fdiv_rn(w.y, CUTOFF)) + 2 + dy;
    int cz = (int)floorf(__fdiv_rn(w.z, CUTOFF)) + 2 + dz;
    int cid = (cx * G + cy) * G + cz;
    int s = starts[cid] + csA[cid >> 10];
    int e = starts[cid + 1] + csA[(cid + 1) >> 10];
    int o = poff[t] + csB[t / PCH];
    for (int q = s; q < e; q++) {
      float4 f = cdata[q];
      float ax = __fsub_rn(f.x, w.x), ay = __fsub_rn(f.y, w.y), az = __fsub_rn(f.z, w.z);
      float d = __fsqrt_rn(__fadd_rn(__fadd_rn(__fmul_rn(ax, ax), __fmul_rn(ay, ay)),
                                     __fmul_rn(az, az)));
      if (d < CUTOFF && d > 0.01f) {
        if (o >= 0 && o < K) {
          int tt = __float_as_int(f.w);
          out[2 * (size_t)o]     = (float)i;
          out[2 * (size_t)o + 1] = (float)(tt / PIMG);
          size_t db = (size_t)2 * K + (size_t)3 * o;
          out[db]     = ax;
          out[db + 1] = ay;
          out[db + 2] = az;
          out[(size_t)5 * K + o] = d;
        }
        o++;
      }
    }
  }
}

extern "C" void kernel_launch(void* const* d_in, const int* in_sizes, int n_in,
                              void* d_out, int out_size, void* d_ws, size_t ws_size,
                              hipStream_t stream) {
  const float* pos  = (const float*)d_in[0];
  const float* cell = (const float*)d_in[1];
  float* out = (float*)d_out;
  int n = in_sizes[0] / 3;
  int K = out_size / 6;
  int n27 = n * PIMG;
  int cap = 8 * n;

  char* ws = (char*)d_ws;
  size_t off = 0;
  auto alloc = [&](size_t bytes) -> char* {
    char* p = ws + off;
    off = (off + bytes + 255) & ~(size_t)255;
    return p;
  };
  // zeroed region first (single memset): bar/Mtot | counts | fill
  int*    bar       = (int*)alloc(256);                 // bar at +0, Mtot at +4
  int*    Mtot      = bar + 1;
  int*    counts    = (int*)alloc((size_t)(NCELLS + 1) * 4);
  int*    fill      = (int*)alloc((size_t)NCELLS * 4);
  size_t  zbytes    = off;
  int*    starts    = (int*)alloc((size_t)(NCELLS + 1) * 4);
  float4* wrapped   = (float4*)alloc((size_t)n * 16);
  int*    chunkSums = (int*)alloc(1024);
  int*    csA       = (int*)alloc(1024);
  int*    blockSum  = (int*)alloc((size_t)NBLK * 4);
  int*    csB       = (int*)alloc((size_t)NBLK * 4);
  int*    poff      = (int*)alloc((size_t)n27 * 4);
  float4* cdata     = (float4*)alloc((size_t)cap * 16);
  if (off > ws_size) return;

  hipMemsetAsync(ws, 0, zbytes, stream);
  k_fused<<<NBLK, NTHR, 0, stream>>>(pos, cell, out, n, K, bar, Mtot, counts, fill,
                                     starts, wrapped, chunkSums, csA, blockSum, csB,
                                     poff, cdata, cap);
}